// Round 3
// baseline (3439.689 us; speedup 1.0000x reference)
//
#include <hip/hip_runtime.h>
#include <hip/hip_cooperative_groups.h>

namespace cg = cooperative_groups;

// Sinkhorn entropic OT, B=16, N=2048, d=3, EPS=0.02, 20 iterations.
// out = (10/16) * sum_b sum_ij P_ij C_ij
//
// Log2-domain streaming LSE with the per-row constant folded OUT of the loop:
//   z_j = u_j + 2S*(p . t)               (3 fma per element; S = log2e/eps)
//   u_next = -log2(N) - (M + log2 Ssum)  [row constant w_i cancels exactly]
// Tables tF (y-side) / tG (x-side) hold float4 (c0,c1,c2,u). Final pass needs
// only table entries: q_i = tG[i].w + Q_CONST, yy recomputed from coords.

namespace {
constexpr int BATCH = 16;
constexpr int NPT   = 2048;
constexpr int BLOCKS_PER_BATCH = 32;        // 64 rows per block
constexpr int ROWS_PER_BLOCK   = 64;
constexpr int NSLICE = 4;                   // j-slices per block (one per wave)
constexpr int JSLICE = NPT / NSLICE;        // 512 j's per thread per phase
constexpr int NBLOCKS  = BATCH * BLOCKS_PER_BATCH;   // 512 (= 2 blocks/CU)
constexpr int NTHREADS = ROWS_PER_BLOCK * NSLICE;    // 256
constexpr int ITERS = 20;
constexpr int CHUNK = 16;

constexpr float SCL     = 72.13475204444817f;     // log2(e)/eps
constexpr float TWOS    = 144.26950408889634f;    // 2*SCL
constexpr float UCONST  = -11.0f;                 // logmu*log2e = -log2(2048)
constexpr float Q_CONST = -22.0f;                 // (logmu+lognu)*log2e

__device__ inline float fexp2(float x) { return __builtin_amdgcn_exp2f(x); }

// One half-iteration: for the thread's row (point p), streaming LSE over the
// 2048-entry table T (slice per wave); write the next phase's table entry.
__device__ inline void half_phase(float p0, float p1, float p2,
                                  const float4* __restrict__ T,
                                  float4* __restrict__ outT,
                                  float* __restrict__ redM,
                                  float* __restrict__ redS,
                                  int batch, int row, int slice, int tid) {
  const float a0 = p0 * TWOS, a1 = p1 * TWOS, a2 = p2 * TWOS;
  const float4* tb = T + (size_t)batch * NPT + slice * JSLICE;

  float m = -3.0e38f;
  float s0 = 0.f, s1 = 0.f;
  for (int c = 0; c < JSLICE; c += CHUNK) {
    float z[CHUNK];
#pragma unroll
    for (int k = 0; k < CHUNK; ++k) {
      float4 t = tb[c + k];
      z[k] = fmaf(a0, t.x, fmaf(a1, t.y, fmaf(a2, t.z, t.w)));
    }
    // chunk max as a max3-fusable tree (~9 instrs / 16 elems)
    float m0 = fmaxf(fmaxf(z[0],  z[1]),  z[2]);
    float m1 = fmaxf(fmaxf(z[3],  z[4]),  z[5]);
    float m2 = fmaxf(fmaxf(z[6],  z[7]),  z[8]);
    float m3 = fmaxf(fmaxf(z[9],  z[10]), z[11]);
    float m4 = fmaxf(fmaxf(z[12], z[13]), z[14]);
    float mn = fmaxf(fmaxf(fmaxf(m0, m1), m2), fmaxf(fmaxf(m3, m4), z[15]));
    float mN = fmaxf(m, mn);
    float r = fexp2(m - mN);   // 0 on first chunk (m=-3e38), 1 when no new max
    s0 *= r; s1 *= r;
    m = mN;
#pragma unroll
    for (int k = 0; k < CHUNK; k += 2) {
      s0 += fexp2(z[k] - m);
      s1 += fexp2(z[k + 1] - m);
    }
  }

  const int lane = tid & (ROWS_PER_BLOCK - 1);
  redM[slice * ROWS_PER_BLOCK + lane] = m;
  redS[slice * ROWS_PER_BLOCK + lane] = s0 + s1;
  __syncthreads();
  if (tid < ROWS_PER_BLOCK) {
    float M = redM[tid], S = redS[tid];
#pragma unroll
    for (int q = 1; q < NSLICE; ++q) {
      float m2q = redM[q * ROWS_PER_BLOCK + tid];
      float s2q = redS[q * ROWS_PER_BLOCK + tid];
      float Mn = fmaxf(M, m2q);
      S = fmaf(S, fexp2(M - Mn), s2q * fexp2(m2q - Mn));
      M = Mn;
    }
    float u = UCONST - (M + __log2f(S));      // == (pot - |p|^2) * SCL
    outT[batch * NPT + row] = make_float4(p0, p1, p2, u);
  }
  // no trailing __syncthreads: a grid.sync() follows every phase
}

__global__ __launch_bounds__(NTHREADS, 2)
void sinkhorn_emd_kernel(const float* __restrict__ X, const float* __restrict__ Y,
                         float* __restrict__ ws, float* __restrict__ out) {
  cg::grid_group grid = cg::this_grid();

  float4* tF = (float4*)ws;              // [B*N]: (y, u_j=(g_j-yy_j)*S)
  float4* tG = tF + BATCH * NPT;         // [B*N]: (x, u_i=(f_i-xx_i)*S)

  const int tid  = threadIdx.x;
  const int bid  = blockIdx.x;
  const int gtid = bid * NTHREADS + tid;

  // ---- init: tableF from y with g=0; zero the output scalar ----
  if (gtid < BATCH * NPT) {
    const float* yp = Y + (size_t)gtid * 3;
    float y0 = yp[0], y1 = yp[1], y2 = yp[2];
    float yy = fmaf(y0, y0, fmaf(y1, y1, y2 * y2));
    tF[gtid] = make_float4(y0, y1, y2, -yy * SCL);   // u_j = (0 - yy)*S
  }
  if (gtid == 0) out[0] = 0.f;

  // XCD-batch affinity: default dispatch round-robins bid across the 8 XCDs
  // (bid&7 == XCD). Map both batches' 32-block groups so each batch's table
  // lives in a single XCD's L2. Pure index permutation — correctness-neutral.
  const int xcd   = bid & 7;
  const int slot  = bid >> 3;                       // 0..63
  const int batch = xcd * 2 + (slot >> 5);          // 2 batches per XCD
  const int rb    = slot & (BLOCKS_PER_BATCH - 1);
  const int lane  = tid & (ROWS_PER_BLOCK - 1);
  const int slice = tid >> 6;
  const int row   = rb * ROWS_PER_BLOCK + lane;
  const int rowIdx = batch * NPT + row;

  // hoist this thread's x-row and y-row (reused in every phase)
  const float* xp = X + (size_t)rowIdx * 3;
  const float px0 = xp[0], px1 = xp[1], px2 = xp[2];
  const float* yp2 = Y + (size_t)rowIdx * 3;
  const float py0 = yp2[0], py1 = yp2[1], py2 = yp2[2];

  grid.sync();

  __shared__ float redM[NSLICE * ROWS_PER_BLOCK];
  __shared__ float redS[NSLICE * ROWS_PER_BLOCK];

  for (int it = 0; it < ITERS; ++it) {
    // F: f_i from stream over (y, g)  -> writes tG
    half_phase(px0, px1, px2, tF, tG, redM, redS, batch, row, slice, tid);
    grid.sync();
    // G: g_j from stream over (x, f)  -> writes tF
    half_phase(py0, py1, py2, tG, tF, redM, redS, batch, row, slice, tid);
    grid.sync();
  }

  // ---- final: sum_ij exp2(lp2) * C_ij ----
  {
    const float nrm = fmaf(px0, px0, fmaf(px1, px1, px2 * px2));
    const float q = tG[rowIdx].w + Q_CONST;          // (f-xx)*S + Q
    const float4* tb = tF + (size_t)batch * NPT + slice * JSLICE;
    float acc = 0.f;
    for (int c = 0; c < JSLICE; c += 4) {
#pragma unroll
      for (int k = 0; k < 4; ++k) {
        float4 t = tb[c + k];
        float dot = fmaf(px2, t.z, fmaf(px1, t.y, px0 * t.x));
        float yy  = fmaf(t.z, t.z, fmaf(t.y, t.y, t.x * t.x));
        float Cij = fmaf(-2.f, dot, nrm + yy);
        float lp  = fmaf(TWOS, dot, q + t.w);        // logP * log2e
        acc = fmaf(fexp2(lp), Cij, acc);
      }
    }
    // wave then block reduction, one atomic per block
    for (int off = 32; off; off >>= 1) acc += __shfl_down(acc, off, 64);
    __shared__ float wsum[NTHREADS / 64];
    if ((tid & 63) == 0) wsum[tid >> 6] = acc;
    __syncthreads();
    if (tid == 0) {
      float tot = 0.f;
#pragma unroll
      for (int k = 0; k < NTHREADS / 64; ++k) tot += wsum[k];
      atomicAdd(out, 0.625f * tot);   // 10/16
    }
  }
}
} // namespace

extern "C" void kernel_launch(void* const* d_in, const int* in_sizes, int n_in,
                              void* d_out, int out_size, void* d_ws, size_t ws_size,
                              hipStream_t stream) {
  const float* X = (const float*)d_in[0];
  const float* Y = (const float*)d_in[1];
  float* out = (float*)d_out;
  float* ws  = (float*)d_ws;

  void* args[] = {(void*)&X, (void*)&Y, (void*)&ws, (void*)&out};
  hipLaunchCooperativeKernel((const void*)sinkhorn_emd_kernel,
                             dim3(NBLOCKS), dim3(NTHREADS),
                             args, 0, stream);
}

// Round 4
// 2914.925 us; speedup vs baseline: 1.1800x; 1.1800x over previous
//
#include <hip/hip_runtime.h>
#include <hip/hip_cooperative_groups.h>

namespace cg = cooperative_groups;

// Sinkhorn entropic OT, B=16, N=2048, d=3, EPS=0.02, 20 iterations.
// out = (10/16) * sum_b sum_ij P_ij C_ij
//
// Log2-domain streaming LSE, per-row constant folded out:
//   z_j = u_j + 2S*(p . t)               (3 fma per element; S = log2e/eps)
//   u_next = -log2(N) - (M + log2 Ssum)
// Tables tF (y-side) / tG (x-side) in global ws hold float4 (c0,c1,c2,u).
//
// R4 change (from profile: VALUBusy=15%, VGPR=32, ~400cy/elem => inner loop
// was a serialized L2-load chain): stage each wave's 8KB table slice into LDS
// once per phase with coalesced per-lane float4 loads, then stream from LDS
// via wave-uniform ds_read_b128 (broadcast, conflict-free).

namespace {
constexpr int BATCH = 16;
constexpr int NPT   = 2048;
constexpr int BLOCKS_PER_BATCH = 32;        // 64 rows per block
constexpr int ROWS_PER_BLOCK   = 64;
constexpr int NSLICE = 4;                   // j-slices per block (one per wave)
constexpr int JSLICE = NPT / NSLICE;        // 512 j's per thread per phase
constexpr int NBLOCKS  = BATCH * BLOCKS_PER_BATCH;   // 512 (= 2 blocks/CU)
constexpr int NTHREADS = ROWS_PER_BLOCK * NSLICE;    // 256
constexpr int ITERS = 20;
constexpr int CHUNK = 16;

constexpr float SCL     = 72.13475204444817f;     // log2(e)/eps
constexpr float TWOS    = 144.26950408889634f;    // 2*SCL
constexpr float UCONST  = -11.0f;                 // logmu*log2e = -log2(2048)
constexpr float Q_CONST = -22.0f;                 // (logmu+lognu)*log2e

__device__ inline float fexp2(float x) { return __builtin_amdgcn_exp2f(x); }

struct Smem {
  float4 tab[NSLICE * JSLICE];          // 32 KB staged table
  float  redM[NSLICE * ROWS_PER_BLOCK]; // 1 KB
  float  redS[NSLICE * ROWS_PER_BLOCK]; // 1 KB
  float  wsum[NTHREADS / 64];
};

// Stage this wave's 512-entry slice of T into LDS (coalesced), then
// streaming LSE over it; write the next phase's table entry.
__device__ inline void half_phase(float p0, float p1, float p2,
                                  const float4* __restrict__ T,
                                  float4* __restrict__ outT,
                                  Smem& sm,
                                  int batch, int row, int slice, int lane, int tid) {
  // ---- stage: 8 coalesced float4 loads per lane, independent (latency paid once)
  {
    const float4* __restrict__ gsrc = T + (size_t)batch * NPT + slice * JSLICE;
    float4* __restrict__ ldst = sm.tab + slice * JSLICE;
#pragma unroll
    for (int k = 0; k < JSLICE / 64; ++k)
      ldst[k * 64 + lane] = gsrc[k * 64 + lane];
  }
  __syncthreads();   // also orders ds_write -> ds_read

  const float a0 = p0 * TWOS, a1 = p1 * TWOS, a2 = p2 * TWOS;
  const float4* __restrict__ tb = sm.tab + slice * JSLICE;

  float m = -3.0e38f;
  float s0 = 0.f, s1 = 0.f;
  for (int c = 0; c < JSLICE; c += CHUNK) {
    float z[CHUNK];
#pragma unroll
    for (int k = 0; k < CHUNK; ++k) {
      float4 t = tb[c + k];               // wave-uniform ds_read_b128 (broadcast)
      z[k] = fmaf(a0, t.x, fmaf(a1, t.y, fmaf(a2, t.z, t.w)));
    }
    float m0 = fmaxf(fmaxf(z[0],  z[1]),  z[2]);
    float m1 = fmaxf(fmaxf(z[3],  z[4]),  z[5]);
    float m2 = fmaxf(fmaxf(z[6],  z[7]),  z[8]);
    float m3 = fmaxf(fmaxf(z[9],  z[10]), z[11]);
    float m4 = fmaxf(fmaxf(z[12], z[13]), z[14]);
    float mn = fmaxf(fmaxf(fmaxf(m0, m1), m2), fmaxf(fmaxf(m3, m4), z[15]));
    float mN = fmaxf(m, mn);
    float r = fexp2(m - mN);   // 0 on first chunk (m=-3e38), 1 when no new max
    s0 *= r; s1 *= r;
    m = mN;
#pragma unroll
    for (int k = 0; k < CHUNK; k += 2) {
      s0 += fexp2(z[k] - m);
      s1 += fexp2(z[k + 1] - m);
    }
  }

  sm.redM[slice * ROWS_PER_BLOCK + lane] = m;
  sm.redS[slice * ROWS_PER_BLOCK + lane] = s0 + s1;
  __syncthreads();
  if (tid < ROWS_PER_BLOCK) {
    float M = sm.redM[tid], S = sm.redS[tid];
#pragma unroll
    for (int q = 1; q < NSLICE; ++q) {
      float m2q = sm.redM[q * ROWS_PER_BLOCK + tid];
      float s2q = sm.redS[q * ROWS_PER_BLOCK + tid];
      float Mn = fmaxf(M, m2q);
      S = fmaf(S, fexp2(M - Mn), s2q * fexp2(m2q - Mn));
      M = Mn;
    }
    float u = UCONST - (M + __log2f(S));      // == (pot - |p|^2) * SCL
    outT[batch * NPT + row] = make_float4(p0, p1, p2, u);
  }
  // no trailing barrier: a grid.sync() follows every phase
}

__global__ __launch_bounds__(NTHREADS, 2)
void sinkhorn_emd_kernel(const float* __restrict__ X, const float* __restrict__ Y,
                         float* __restrict__ ws, float* __restrict__ out) {
  cg::grid_group grid = cg::this_grid();

  float4* tF = (float4*)ws;              // [B*N]: (y, u_j=(g_j-yy_j)*S)
  float4* tG = tF + BATCH * NPT;         // [B*N]: (x, u_i=(f_i-xx_i)*S)

  const int tid  = threadIdx.x;
  const int bid  = blockIdx.x;
  const int gtid = bid * NTHREADS + tid;

  __shared__ Smem sm;

  // ---- init: tableF from y with g=0; zero the output scalar ----
  if (gtid < BATCH * NPT) {
    const float* yp = Y + (size_t)gtid * 3;
    float y0 = yp[0], y1 = yp[1], y2 = yp[2];
    float yy = fmaf(y0, y0, fmaf(y1, y1, y2 * y2));
    tF[gtid] = make_float4(y0, y1, y2, -yy * SCL);   // u_j = (0 - yy)*S
  }
  if (gtid == 0) out[0] = 0.f;

  // XCD-batch affinity: bid&7 == XCD on the default round-robin dispatch;
  // keep each batch's 32-block group (and its table) on one XCD's L2.
  const int xcd   = bid & 7;
  const int slot  = bid >> 3;                       // 0..63
  const int batch = xcd * 2 + (slot >> 5);          // 2 batches per XCD
  const int rb    = slot & (BLOCKS_PER_BATCH - 1);
  const int lane  = tid & (ROWS_PER_BLOCK - 1);
  const int slice = tid >> 6;
  const int row   = rb * ROWS_PER_BLOCK + lane;
  const int rowIdx = batch * NPT + row;

  // hoist this thread's x-row and y-row (reused in every phase)
  const float* xp = X + (size_t)rowIdx * 3;
  const float px0 = xp[0], px1 = xp[1], px2 = xp[2];
  const float* yp2 = Y + (size_t)rowIdx * 3;
  const float py0 = yp2[0], py1 = yp2[1], py2 = yp2[2];

  grid.sync();

  for (int it = 0; it < ITERS; ++it) {
    // F: f_i from stream over (y, g)  -> writes tG
    half_phase(px0, px1, px2, tF, tG, sm, batch, row, slice, lane, tid);
    grid.sync();
    // G: g_j from stream over (x, f)  -> writes tF
    half_phase(py0, py1, py2, tG, tF, sm, batch, row, slice, lane, tid);
    grid.sync();
  }

  // ---- final: sum_ij exp2(lp2) * C_ij (stream tF slice from LDS again) ----
  {
    {
      const float4* __restrict__ gsrc = tF + (size_t)batch * NPT + slice * JSLICE;
      float4* __restrict__ ldst = sm.tab + slice * JSLICE;
#pragma unroll
      for (int k = 0; k < JSLICE / 64; ++k)
        ldst[k * 64 + lane] = gsrc[k * 64 + lane];
    }
    __syncthreads();

    const float nrm = fmaf(px0, px0, fmaf(px1, px1, px2 * px2));
    const float q = tG[rowIdx].w + Q_CONST;          // (f-xx)*S + Q
    const float4* __restrict__ tb = sm.tab + slice * JSLICE;
    float acc = 0.f;
    for (int c = 0; c < JSLICE; c += 4) {
#pragma unroll
      for (int k = 0; k < 4; ++k) {
        float4 t = tb[c + k];
        float dot = fmaf(px2, t.z, fmaf(px1, t.y, px0 * t.x));
        float yy  = fmaf(t.z, t.z, fmaf(t.y, t.y, t.x * t.x));
        float Cij = fmaf(-2.f, dot, nrm + yy);
        float lp  = fmaf(TWOS, dot, q + t.w);        // logP * log2e
        acc = fmaf(fexp2(lp), Cij, acc);
      }
    }
    // wave then block reduction, one atomic per block
    for (int off = 32; off; off >>= 1) acc += __shfl_down(acc, off, 64);
    if ((tid & 63) == 0) sm.wsum[tid >> 6] = acc;
    __syncthreads();
    if (tid == 0) {
      float tot = 0.f;
#pragma unroll
      for (int k = 0; k < NTHREADS / 64; ++k) tot += sm.wsum[k];
      atomicAdd(out, 0.625f * tot);   // 10/16
    }
  }
}
} // namespace

extern "C" void kernel_launch(void* const* d_in, const int* in_sizes, int n_in,
                              void* d_out, int out_size, void* d_ws, size_t ws_size,
                              hipStream_t stream) {
  const float* X = (const float*)d_in[0];
  const float* Y = (const float*)d_in[1];
  float* out = (float*)d_out;
  float* ws  = (float*)d_ws;

  void* args[] = {(void*)&X, (void*)&Y, (void*)&ws, (void*)&out};
  hipLaunchCooperativeKernel((const void*)sinkhorn_emd_kernel,
                             dim3(NBLOCKS), dim3(NTHREADS),
                             args, 0, stream);
}

// Round 5
// 1283.115 us; speedup vs baseline: 2.6807x; 2.2718x over previous
//
#include <hip/hip_runtime.h>

// Sinkhorn entropic OT, B=16, N=2048, d=3, EPS=0.02, 20 iterations.
// out = (10/16) * sum_b sum_ij P_ij C_ij
//
// Log2-domain streaming LSE, per-row constant folded out:
//   z_j = u_j + 2S*(p . t)               (3 fma per element; S = log2e/eps)
//   u_next = -log2(N) - (M + log2 Ssum)
// Tables tF (y-side) / tG (x-side) in global ws hold float4 (c0,c1,c2,u).
//
// R5 change (from profile: VALU-busy TIME constant at ~520us across R3/R4
// while dur ~2.9ms => ~2.4ms is barrier overhead, i.e. 41 x cg::grid.sync()
// at ~60us each): replace the 40 in-loop grid-wide syncs with per-batch
// 32-block arrive-and-wait barriers (monotonic counter in ws, agent-scope
// release/acquire atomics). One global barrier remains after init.
// Cooperative launch kept only for the co-residency guarantee.

namespace {
constexpr int BATCH = 16;
constexpr int NPT   = 2048;
constexpr int BLOCKS_PER_BATCH = 32;        // 64 rows per block
constexpr int ROWS_PER_BLOCK   = 64;
constexpr int NSLICE = 4;                   // j-slices per block (one per wave)
constexpr int JSLICE = NPT / NSLICE;        // 512 j's per thread per phase
constexpr int NBLOCKS  = BATCH * BLOCKS_PER_BATCH;   // 512 (= 2 blocks/CU)
constexpr int NTHREADS = ROWS_PER_BLOCK * NSLICE;    // 256
constexpr int ITERS = 20;
constexpr int CHUNK = 16;

constexpr int BAR_STRIDE = 32;              // uints between counters (128B pad)
constexpr int BAR_BYTES  = 4096;            // zeroed via hipMemsetAsync pre-launch

constexpr float SCL     = 72.13475204444817f;     // log2(e)/eps
constexpr float TWOS    = 144.26950408889634f;    // 2*SCL
constexpr float UCONST  = -11.0f;                 // logmu*log2e = -log2(2048)
constexpr float Q_CONST = -22.0f;                 // (logmu+lognu)*log2e

__device__ inline float fexp2(float x) { return __builtin_amdgcn_exp2f(x); }

struct Smem {
  float4 tab[NSLICE * JSLICE];          // 32 KB staged table
  float  redM[NSLICE * ROWS_PER_BLOCK]; // 1 KB
  float  redS[NSLICE * ROWS_PER_BLOCK]; // 1 KB
  float  wsum[NTHREADS / 64];
};

// Inter-block arrive-and-wait on a monotonic counter (device/agent scope,
// correct regardless of XCD placement; swizzle below only makes it fast).
__device__ inline void arrive_and_wait(unsigned* bar, unsigned target, int tid) {
  __syncthreads();                        // block done with previous phase
  if (tid == 0) {
    __hip_atomic_fetch_add(bar, 1u, __ATOMIC_RELEASE, __HIP_MEMORY_SCOPE_AGENT);
    while (__hip_atomic_load(bar, __ATOMIC_ACQUIRE, __HIP_MEMORY_SCOPE_AGENT) < target) {}
  }
  __syncthreads();                        // all threads see the acquire
}

// Stage this wave's 512-entry slice of T into LDS (coalesced), then
// streaming LSE over it; write the next phase's table entry.
__device__ inline void half_phase(float p0, float p1, float p2,
                                  const float4* __restrict__ T,
                                  float4* __restrict__ outT,
                                  Smem& sm,
                                  int batch, int row, int slice, int lane, int tid) {
  // ---- stage: 8 coalesced float4 loads per lane, independent
  {
    const float4* __restrict__ gsrc = T + (size_t)batch * NPT + slice * JSLICE;
    float4* __restrict__ ldst = sm.tab + slice * JSLICE;
#pragma unroll
    for (int k = 0; k < JSLICE / 64; ++k)
      ldst[k * 64 + lane] = gsrc[k * 64 + lane];
  }
  __syncthreads();   // orders ds_write -> ds_read

  const float a0 = p0 * TWOS, a1 = p1 * TWOS, a2 = p2 * TWOS;
  const float4* __restrict__ tb = sm.tab + slice * JSLICE;

  float m = -3.0e38f;
  float s0 = 0.f, s1 = 0.f;
  for (int c = 0; c < JSLICE; c += CHUNK) {
    float z[CHUNK];
#pragma unroll
    for (int k = 0; k < CHUNK; ++k) {
      float4 t = tb[c + k];               // wave-uniform ds_read_b128 (broadcast)
      z[k] = fmaf(a0, t.x, fmaf(a1, t.y, fmaf(a2, t.z, t.w)));
    }
    float m0 = fmaxf(fmaxf(z[0],  z[1]),  z[2]);
    float m1 = fmaxf(fmaxf(z[3],  z[4]),  z[5]);
    float m2 = fmaxf(fmaxf(z[6],  z[7]),  z[8]);
    float m3 = fmaxf(fmaxf(z[9],  z[10]), z[11]);
    float m4 = fmaxf(fmaxf(z[12], z[13]), z[14]);
    float mn = fmaxf(fmaxf(fmaxf(m0, m1), m2), fmaxf(fmaxf(m3, m4), z[15]));
    float mN = fmaxf(m, mn);
    float r = fexp2(m - mN);   // 0 on first chunk (m=-3e38), 1 when no new max
    s0 *= r; s1 *= r;
    m = mN;
#pragma unroll
    for (int k = 0; k < CHUNK; k += 2) {
      s0 += fexp2(z[k] - m);
      s1 += fexp2(z[k + 1] - m);
    }
  }

  sm.redM[slice * ROWS_PER_BLOCK + lane] = m;
  sm.redS[slice * ROWS_PER_BLOCK + lane] = s0 + s1;
  __syncthreads();
  if (tid < ROWS_PER_BLOCK) {
    float M = sm.redM[tid], S = sm.redS[tid];
#pragma unroll
    for (int q = 1; q < NSLICE; ++q) {
      float m2q = sm.redM[q * ROWS_PER_BLOCK + tid];
      float s2q = sm.redS[q * ROWS_PER_BLOCK + tid];
      float Mn = fmaxf(M, m2q);
      S = fmaf(S, fexp2(M - Mn), s2q * fexp2(m2q - Mn));
      M = Mn;
    }
    float u = UCONST - (M + __log2f(S));      // == (pot - |p|^2) * SCL
    outT[batch * NPT + row] = make_float4(p0, p1, p2, u);
  }
  // no trailing barrier: an arrive_and_wait follows every phase
}

__global__ __launch_bounds__(NTHREADS, 2)
void sinkhorn_emd_kernel(const float* __restrict__ X, const float* __restrict__ Y,
                         float* __restrict__ ws, float* __restrict__ out) {
  unsigned* __restrict__ bars = (unsigned*)ws;            // [1024] zeroed pre-launch
  float4* tF = (float4*)((char*)ws + BAR_BYTES);          // [B*N]: (y, u_j)
  float4* tG = tF + BATCH * NPT;                          // [B*N]: (x, u_i)

  const int tid  = threadIdx.x;
  const int bid  = blockIdx.x;
  const int gtid = bid * NTHREADS + tid;

  __shared__ Smem sm;

  // ---- init: tableF from y with g=0; zero the output scalar ----
  if (gtid < BATCH * NPT) {
    const float* yp = Y + (size_t)gtid * 3;
    float y0 = yp[0], y1 = yp[1], y2 = yp[2];
    float yy = fmaf(y0, y0, fmaf(y1, y1, y2 * y2));
    tF[gtid] = make_float4(y0, y1, y2, -yy * SCL);   // u_j = (0 - yy)*S
  }
  if (gtid == 0) out[0] = 0.f;

  // XCD-batch affinity: bid&7 == XCD on the default round-robin dispatch;
  // keep each batch's 32-block group (tables + barrier line) on one XCD's L2.
  const int xcd   = bid & 7;
  const int slot  = bid >> 3;                       // 0..63
  const int batch = xcd * 2 + (slot >> 5);          // 2 batches per XCD
  const int rb    = slot & (BLOCKS_PER_BATCH - 1);
  const int lane  = tid & (ROWS_PER_BLOCK - 1);
  const int slice = tid >> 6;
  const int row   = rb * ROWS_PER_BLOCK + lane;
  const int rowIdx = batch * NPT + row;

  // hoist this thread's x-row and y-row (reused in every phase)
  const float* xp = X + (size_t)rowIdx * 3;
  const float px0 = xp[0], px1 = xp[1], px2 = xp[2];
  const float* yp2 = Y + (size_t)rowIdx * 3;
  const float py0 = yp2[0], py1 = yp2[1], py2 = yp2[2];

  // one global barrier: orders init (tables + out[0]) before everything
  arrive_and_wait(bars + 512, NBLOCKS, tid);

  unsigned* __restrict__ bar = bars + batch * BAR_STRIDE;
  unsigned targ = BLOCKS_PER_BATCH;

  for (int it = 0; it < ITERS; ++it) {
    // F: f_i from stream over (y, g)  -> writes tG
    half_phase(px0, px1, px2, tF, tG, sm, batch, row, slice, lane, tid);
    arrive_and_wait(bar, targ, tid); targ += BLOCKS_PER_BATCH;
    // G: g_j from stream over (x, f)  -> writes tF
    half_phase(py0, py1, py2, tG, tF, sm, batch, row, slice, lane, tid);
    arrive_and_wait(bar, targ, tid); targ += BLOCKS_PER_BATCH;
  }

  // ---- final: sum_ij exp2(lp2) * C_ij (stream tF slice from LDS again) ----
  {
    {
      const float4* __restrict__ gsrc = tF + (size_t)batch * NPT + slice * JSLICE;
      float4* __restrict__ ldst = sm.tab + slice * JSLICE;
#pragma unroll
      for (int k = 0; k < JSLICE / 64; ++k)
        ldst[k * 64 + lane] = gsrc[k * 64 + lane];
    }
    __syncthreads();

    const float nrm = fmaf(px0, px0, fmaf(px1, px1, px2 * px2));
    const float q = tG[rowIdx].w + Q_CONST;          // (f-xx)*S + Q
    const float4* __restrict__ tb = sm.tab + slice * JSLICE;
    float acc = 0.f;
    for (int c = 0; c < JSLICE; c += 4) {
#pragma unroll
      for (int k = 0; k < 4; ++k) {
        float4 t = tb[c + k];
        float dot = fmaf(px2, t.z, fmaf(px1, t.y, px0 * t.x));
        float yy  = fmaf(t.z, t.z, fmaf(t.y, t.y, t.x * t.x));
        float Cij = fmaf(-2.f, dot, nrm + yy);
        float lp  = fmaf(TWOS, dot, q + t.w);        // logP * log2e
        acc = fmaf(fexp2(lp), Cij, acc);
      }
    }
    // wave then block reduction, one atomic per block
    for (int off = 32; off; off >>= 1) acc += __shfl_down(acc, off, 64);
    if ((tid & 63) == 0) sm.wsum[tid >> 6] = acc;
    __syncthreads();
    if (tid == 0) {
      float tot = 0.f;
#pragma unroll
      for (int k = 0; k < NTHREADS / 64; ++k) tot += sm.wsum[k];
      atomicAdd(out, 0.625f * tot);   // 10/16
    }
  }
}
} // namespace

extern "C" void kernel_launch(void* const* d_in, const int* in_sizes, int n_in,
                              void* d_out, int out_size, void* d_ws, size_t ws_size,
                              hipStream_t stream) {
  const float* X = (const float*)d_in[0];
  const float* Y = (const float*)d_in[1];
  float* out = (float*)d_out;
  float* ws  = (float*)d_ws;

  // zero the barrier counters (ws is poisoned 0xAA before every launch)
  hipMemsetAsync(ws, 0, BAR_BYTES, stream);

  void* args[] = {(void*)&X, (void*)&Y, (void*)&ws, (void*)&out};
  hipLaunchCooperativeKernel((const void*)sinkhorn_emd_kernel,
                             dim3(NBLOCKS), dim3(NTHREADS),
                             args, 0, stream);
}

// Round 10
// 1276.131 us; speedup vs baseline: 2.6954x; 1.0055x over previous
//
#include <hip/hip_runtime.h>

// Sinkhorn entropic OT, B=16, N=2048, d=3, EPS=0.02, 20 iterations.
// out = (10/16) * sum_b sum_ij P_ij C_ij
//
// Log2-domain streaming LSE, per-row constant folded out:
//   z_j = u_j + 2S*(p . t)               (3 fma per element; S = log2e/eps)
//   u_next = -log2(N) - (M + log2 Ssum)
// Tables tF (y-side) / tG (x-side) in global ws hold float4 (c0,c1,c2,u).
//
// R10: R9's controlled A/B never ran (GPU acquisition timeout). Resubmitting
// the EXACT R5 source (passed: absmax 0.0, 1283us) unchanged. R6/R7/R8 failed
// with BIT-IDENTICAL error (2.374873e-07 = exactly 50x threshold = 1/EPS x
// one potential quantum) despite an empty intersection of source changes ->
// suspect environment/reference drift rather than kernel bits. If this run
// passes, bisect kernel-side next; if it fails identically, the reference
// moved and bit-chasing the kernel is futile.

namespace {
constexpr int BATCH = 16;
constexpr int NPT   = 2048;
constexpr int BLOCKS_PER_BATCH = 32;        // 64 rows per block
constexpr int ROWS_PER_BLOCK   = 64;
constexpr int NSLICE = 4;                   // j-slices per block (one per wave)
constexpr int JSLICE = NPT / NSLICE;        // 512 j's per thread per phase
constexpr int NBLOCKS  = BATCH * BLOCKS_PER_BATCH;   // 512 (= 2 blocks/CU)
constexpr int NTHREADS = ROWS_PER_BLOCK * NSLICE;    // 256
constexpr int ITERS = 20;
constexpr int CHUNK = 16;

constexpr int BAR_STRIDE = 32;              // uints between counters (128B pad)
constexpr int BAR_BYTES  = 4096;            // zeroed via hipMemsetAsync pre-launch

constexpr float SCL     = 72.13475204444817f;     // log2(e)/eps
constexpr float TWOS    = 144.26950408889634f;    // 2*SCL
constexpr float UCONST  = -11.0f;                 // logmu*log2e = -log2(2048)
constexpr float Q_CONST = -22.0f;                 // (logmu+lognu)*log2e

__device__ inline float fexp2(float x) { return __builtin_amdgcn_exp2f(x); }

struct Smem {
  float4 tab[NSLICE * JSLICE];          // 32 KB staged table
  float  redM[NSLICE * ROWS_PER_BLOCK]; // 1 KB
  float  redS[NSLICE * ROWS_PER_BLOCK]; // 1 KB
  float  wsum[NTHREADS / 64];
};

// Inter-block arrive-and-wait on a monotonic counter (device/agent scope,
// correct regardless of XCD placement; swizzle below only makes it fast).
__device__ inline void arrive_and_wait(unsigned* bar, unsigned target, int tid) {
  __syncthreads();                        // block done with previous phase
  if (tid == 0) {
    __hip_atomic_fetch_add(bar, 1u, __ATOMIC_RELEASE, __HIP_MEMORY_SCOPE_AGENT);
    while (__hip_atomic_load(bar, __ATOMIC_ACQUIRE, __HIP_MEMORY_SCOPE_AGENT) < target) {}
  }
  __syncthreads();                        // all threads see the acquire
}

// Stage this wave's 512-entry slice of T into LDS (coalesced), then
// streaming LSE over it; write the next phase's table entry.
__device__ inline void half_phase(float p0, float p1, float p2,
                                  const float4* __restrict__ T,
                                  float4* __restrict__ outT,
                                  Smem& sm,
                                  int batch, int row, int slice, int lane, int tid) {
  // ---- stage: 8 coalesced float4 loads per lane, independent
  {
    const float4* __restrict__ gsrc = T + (size_t)batch * NPT + slice * JSLICE;
    float4* __restrict__ ldst = sm.tab + slice * JSLICE;
#pragma unroll
    for (int k = 0; k < JSLICE / 64; ++k)
      ldst[k * 64 + lane] = gsrc[k * 64 + lane];
  }
  __syncthreads();   // orders ds_write -> ds_read

  const float a0 = p0 * TWOS, a1 = p1 * TWOS, a2 = p2 * TWOS;
  const float4* __restrict__ tb = sm.tab + slice * JSLICE;

  float m = -3.0e38f;
  float s0 = 0.f, s1 = 0.f;
  for (int c = 0; c < JSLICE; c += CHUNK) {
    float z[CHUNK];
#pragma unroll
    for (int k = 0; k < CHUNK; ++k) {
      float4 t = tb[c + k];               // wave-uniform ds_read_b128 (broadcast)
      z[k] = fmaf(a0, t.x, fmaf(a1, t.y, fmaf(a2, t.z, t.w)));
    }
    float m0 = fmaxf(fmaxf(z[0],  z[1]),  z[2]);
    float m1 = fmaxf(fmaxf(z[3],  z[4]),  z[5]);
    float m2 = fmaxf(fmaxf(z[6],  z[7]),  z[8]);
    float m3 = fmaxf(fmaxf(z[9],  z[10]), z[11]);
    float m4 = fmaxf(fmaxf(z[12], z[13]), z[14]);
    float mn = fmaxf(fmaxf(fmaxf(m0, m1), m2), fmaxf(fmaxf(m3, m4), z[15]));
    float mN = fmaxf(m, mn);
    float r = fexp2(m - mN);   // 0 on first chunk (m=-3e38), 1 when no new max
    s0 *= r; s1 *= r;
    m = mN;
#pragma unroll
    for (int k = 0; k < CHUNK; k += 2) {
      s0 += fexp2(z[k] - m);
      s1 += fexp2(z[k + 1] - m);
    }
  }

  sm.redM[slice * ROWS_PER_BLOCK + lane] = m;
  sm.redS[slice * ROWS_PER_BLOCK + lane] = s0 + s1;
  __syncthreads();
  if (tid < ROWS_PER_BLOCK) {
    float M = sm.redM[tid], S = sm.redS[tid];
#pragma unroll
    for (int q = 1; q < NSLICE; ++q) {
      float m2q = sm.redM[q * ROWS_PER_BLOCK + tid];
      float s2q = sm.redS[q * ROWS_PER_BLOCK + tid];
      float Mn = fmaxf(M, m2q);
      S = fmaf(S, fexp2(M - Mn), s2q * fexp2(m2q - Mn));
      M = Mn;
    }
    float u = UCONST - (M + __log2f(S));      // == (pot - |p|^2) * SCL
    outT[batch * NPT + row] = make_float4(p0, p1, p2, u);
  }
  // no trailing barrier: an arrive_and_wait follows every phase
}

__global__ __launch_bounds__(NTHREADS, 2)
void sinkhorn_emd_kernel(const float* __restrict__ X, const float* __restrict__ Y,
                         float* __restrict__ ws, float* __restrict__ out) {
  unsigned* __restrict__ bars = (unsigned*)ws;            // [1024] zeroed pre-launch
  float4* tF = (float4*)((char*)ws + BAR_BYTES);          // [B*N]: (y, u_j)
  float4* tG = tF + BATCH * NPT;                          // [B*N]: (x, u_i)

  const int tid  = threadIdx.x;
  const int bid  = blockIdx.x;
  const int gtid = bid * NTHREADS + tid;

  __shared__ Smem sm;

  // ---- init: tableF from y with g=0; zero the output scalar ----
  if (gtid < BATCH * NPT) {
    const float* yp = Y + (size_t)gtid * 3;
    float y0 = yp[0], y1 = yp[1], y2 = yp[2];
    float yy = fmaf(y0, y0, fmaf(y1, y1, y2 * y2));
    tF[gtid] = make_float4(y0, y1, y2, -yy * SCL);   // u_j = (0 - yy)*S
  }
  if (gtid == 0) out[0] = 0.f;

  // XCD-batch affinity: bid&7 == XCD on the default round-robin dispatch;
  // keep each batch's 32-block group (tables + barrier line) on one XCD's L2.
  const int xcd   = bid & 7;
  const int slot  = bid >> 3;                       // 0..63
  const int batch = xcd * 2 + (slot >> 5);          // 2 batches per XCD
  const int rb    = slot & (BLOCKS_PER_BATCH - 1);
  const int lane  = tid & (ROWS_PER_BLOCK - 1);
  const int slice = tid >> 6;
  const int row   = rb * ROWS_PER_BLOCK + lane;
  const int rowIdx = batch * NPT + row;

  // hoist this thread's x-row and y-row (reused in every phase)
  const float* xp = X + (size_t)rowIdx * 3;
  const float px0 = xp[0], px1 = xp[1], px2 = xp[2];
  const float* yp2 = Y + (size_t)rowIdx * 3;
  const float py0 = yp2[0], py1 = yp2[1], py2 = yp2[2];

  // one global barrier: orders init (tables + out[0]) before everything
  arrive_and_wait(bars + 512, NBLOCKS, tid);

  unsigned* __restrict__ bar = bars + batch * BAR_STRIDE;
  unsigned targ = BLOCKS_PER_BATCH;

  for (int it = 0; it < ITERS; ++it) {
    // F: f_i from stream over (y, g)  -> writes tG
    half_phase(px0, px1, px2, tF, tG, sm, batch, row, slice, lane, tid);
    arrive_and_wait(bar, targ, tid); targ += BLOCKS_PER_BATCH;
    // G: g_j from stream over (x, f)  -> writes tF
    half_phase(py0, py1, py2, tG, tF, sm, batch, row, slice, lane, tid);
    arrive_and_wait(bar, targ, tid); targ += BLOCKS_PER_BATCH;
  }

  // ---- final: sum_ij exp2(lp2) * C_ij (stream tF slice from LDS again) ----
  {
    {
      const float4* __restrict__ gsrc = tF + (size_t)batch * NPT + slice * JSLICE;
      float4* __restrict__ ldst = sm.tab + slice * JSLICE;
#pragma unroll
      for (int k = 0; k < JSLICE / 64; ++k)
        ldst[k * 64 + lane] = gsrc[k * 64 + lane];
    }
    __syncthreads();

    const float nrm = fmaf(px0, px0, fmaf(px1, px1, px2 * px2));
    const float q = tG[rowIdx].w + Q_CONST;          // (f-xx)*S + Q
    const float4* __restrict__ tb = sm.tab + slice * JSLICE;
    float acc = 0.f;
    for (int c = 0; c < JSLICE; c += 4) {
#pragma unroll
      for (int k = 0; k < 4; ++k) {
        float4 t = tb[c + k];
        float dot = fmaf(px2, t.z, fmaf(px1, t.y, px0 * t.x));
        float yy  = fmaf(t.z, t.z, fmaf(t.y, t.y, t.x * t.x));
        float Cij = fmaf(-2.f, dot, nrm + yy);
        float lp  = fmaf(TWOS, dot, q + t.w);        // logP * log2e
        acc = fmaf(fexp2(lp), Cij, acc);
      }
    }
    // wave then block reduction, one atomic per block
    for (int off = 32; off; off >>= 1) acc += __shfl_down(acc, off, 64);
    if ((tid & 63) == 0) sm.wsum[tid >> 6] = acc;
    __syncthreads();
    if (tid == 0) {
      float tot = 0.f;
#pragma unroll
      for (int k = 0; k < NTHREADS / 64; ++k) tot += sm.wsum[k];
      atomicAdd(out, 0.625f * tot);   // 10/16
    }
  }
}
} // namespace

extern "C" void kernel_launch(void* const* d_in, const int* in_sizes, int n_in,
                              void* d_out, int out_size, void* d_ws, size_t ws_size,
                              hipStream_t stream) {
  const float* X = (const float*)d_in[0];
  const float* Y = (const float*)d_in[1];
  float* out = (float*)d_out;
  float* ws  = (float*)d_ws;

  // zero the barrier counters (ws is poisoned 0xAA before every launch)
  hipMemsetAsync(ws, 0, BAR_BYTES, stream);

  void* args[] = {(void*)&X, (void*)&Y, (void*)&ws, (void*)&out};
  hipLaunchCooperativeKernel((const void*)sinkhorn_emd_kernel,
                             dim3(NBLOCKS), dim3(NTHREADS),
                             args, 0, stream);
}